// Round 8
// baseline (222.990 us; speedup 1.0000x reference)
//
#include <hip/hip_runtime.h>
#include <hip/hip_bf16.h>
#include <cstdint>

typedef unsigned short u16;
typedef __attribute__((ext_vector_type(8))) short bf16x8;
typedef __attribute__((ext_vector_type(4))) float f32x4;

#define T_SEQ 2048
#define NHEAD 16
#define HDIM  64
#define NB    2

__device__ __forceinline__ float bf2f(uint32_t h) { return __uint_as_float(h << 16); }
__device__ __forceinline__ u16 f2bf(float f) {
    uint32_t u = __float_as_uint(f);
    u += 0x7fffu + ((u >> 16) & 1u);
    return (u16)(u >> 16);
}

// async global->LDS, 16B per lane; LDS dest = wave-uniform base + lane*16
__device__ __forceinline__ void gl_lds16(const u16* g, u16* s) {
    __builtin_amdgcn_global_load_lds(
        (const __attribute__((address_space(1))) unsigned int*)g,
        (__attribute__((address_space(3))) unsigned int*)s, 16, 0, 0);
}

// Detect input dtype: bf16-packed data has low-u16 exponent fields clustered
// near 127; fp32 low halves are ~uniform mantissa bits.
__global__ void detect_dtype(const uint32_t* __restrict__ x, int* __restrict__ flag) {
    if (threadIdx.x == 0 && blockIdx.x == 0) {
        int cnt = 0;
        for (int i = 0; i < 1024; i++) {
            uint32_t lo = x[i] & 0xffffu;
            uint32_t e = (lo >> 7) & 0xffu;
            if (lo != 0u && e >= 110u && e <= 135u) cnt++;
        }
        *flag = (cnt > 614) ? 1 : 0;   // 1 = inputs bf16, 0 = fp32
    }
}

// vectorized conversion, 4 elements per thread
__global__ __launch_bounds__(256) void to_bf16(
    const void* __restrict__ src, u16* __restrict__ dst, int n4,
    const int* __restrict__ flag)
{
    int i = blockIdx.x * 256 + threadIdx.x;
    const int stride = gridDim.x * 256;
    if (*flag != 0) {
        const uint2* s = (const uint2*)src;
        uint2* d = (uint2*)dst;
        for (; i < n4; i += stride) d[i] = s[i];
    } else {
        const float4* s = (const float4*)src;
        for (; i < n4; i += stride) {
            float4 v = s[i];
            ushort4 o = { f2bf(v.x), f2bf(v.y), f2bf(v.z), f2bf(v.w) };
            *(ushort4*)(dst + (size_t)i * 4) = o;
        }
    }
}

// m97-pattern MFMA GEMM: C = A (MxK bf16 rm) * B^T (B NxK rm), fp32 accum.
// global_load_lds width-16 staging into unpadded [BM][64] LDS tiles with XOR
// swizzle (LDS chunk c of row r holds global chunk c^(r&7)) -> conflict-free
// stride-64 fragment reads. 4 waves in 2x2, no register staging buffers.
// MODE 0 (BM=128): scatter q [b,h,t,d] (x0.125), k [b,h,t,d], vT [b,h,d,t].
// MODE 1 (BM=64): row-major C; fp32 (flag==0) or bf16 path, full-line stores.
template<int BM, int MODE>
__global__ __launch_bounds__(256, 3) void gemm_bt_mfma(
    const u16* __restrict__ A, const u16* __restrict__ B,
    int N, int K,
    u16* __restrict__ qo, u16* __restrict__ ko, u16* __restrict__ vt,
    u16* __restrict__ outb16, float* __restrict__ outf32,
    const int* __restrict__ flag)
{
    constexpr int WM = BM / 2;
    constexpr int MI = WM / 16;
    constexpr int IA = BM / 32;   // global_load_lds instrs per wave per matrix
    constexpr int ST = 2 * BM * 64 * 2;                       // staging bytes
    constexpr int E16 = 4 * WM * 72 * 2;                      // u16 epilogue bytes
    constexpr int EF = (MODE == 1) ? 4 * WM * (WM + 4) * 4 : 0;  // f32 epilogue
    constexpr int SB = (ST > E16 ? ST : E16) > EF ? (ST > E16 ? ST : E16) : EF;
    __shared__ u16 smem[SB / 2];
    u16* As = smem;            // [BM][64]
    u16* Bs = smem + BM * 64;  // [BM][64]
    const int tid = threadIdx.x;
    const int bm = blockIdx.y * BM, bn = blockIdx.x * BM;
    const int w = tid >> 6, lane = tid & 63;
    const int wm = (w >> 1) * WM, wn = (w & 1) * WM;
    const int n16 = lane & 15, quad = lane >> 4;
    const int l8 = lane >> 3, c8 = lane & 7;

    f32x4 acc[MI][MI];
#pragma unroll
    for (int mi = 0; mi < MI; mi++)
#pragma unroll
        for (int ni = 0; ni < MI; ni++) acc[mi][ni] = (f32x4){0.f, 0.f, 0.f, 0.f};

    const int KT = K >> 6;
    for (int kt = 0; kt < KT; kt++) {
        const int k0 = kt << 6;
#pragma unroll
        for (int i = 0; i < IA; i++) {
            int rowblk = (i * 4 + w) * 8;
            int row = rowblk + l8;
            int gcol = (c8 ^ l8) * 8;   // XOR swizzle: LDS chunk c holds global chunk c^(row&7)
            gl_lds16(A + (size_t)(bm + row) * K + k0 + gcol, As + rowblk * 64);
            gl_lds16(B + (size_t)(bn + row) * K + k0 + gcol, Bs + rowblk * 64);
        }
        __syncthreads();   // drains vmcnt before barrier
#pragma unroll
        for (int ks = 0; ks < 2; ks++) {
            bf16x8 af[MI], bfr[MI];
#pragma unroll
            for (int mi = 0; mi < MI; mi++) {
                int row = wm + mi * 16 + n16;
                af[mi] = *(const bf16x8*)(As + row * 64 + (((ks * 4 + quad) ^ (n16 & 7)) * 8));
            }
#pragma unroll
            for (int ni = 0; ni < MI; ni++) {
                int row = wn + ni * 16 + n16;
                bfr[ni] = *(const bf16x8*)(Bs + row * 64 + (((ks * 4 + quad) ^ (n16 & 7)) * 8));
            }
#pragma unroll
            for (int mi = 0; mi < MI; mi++)
#pragma unroll
                for (int ni = 0; ni < MI; ni++)
                    acc[mi][ni] = __builtin_amdgcn_mfma_f32_16x16x32_bf16(
                        af[mi], bfr[ni], acc[mi][ni], 0, 0, 0);
        }
        __syncthreads();   // all reads done before next stage overwrites
    }

    // Epilogues: per-wave LDS transpose -> full-line stores.
    // C/D layout: col = n16, row = quad*4 + r (HW-verified m89/m91).
    if constexpr (MODE == 0) {
        u16* ep = smem + w * (WM * 72);
        const int which = (bn + wn) >> 10;            // wave-uniform: 0=q 1=k 2=v
        const int hq = ((bn + wn) & 1023) >> 6;
        const int bb = (bm + wm) >> 11;
        const int tb = (bm + wm) & (T_SEQ - 1);
        if (which == 2) {
            // transpose: ep rows are d, cols are t
#pragma unroll
            for (int mi = 0; mi < MI; mi++)
#pragma unroll
                for (int ni = 0; ni < MI; ni++)
#pragma unroll
                    for (int r = 0; r < 4; r++)
                        ep[(ni * 16 + n16) * 72 + mi * 16 + quad * 4 + r] = f2bf(acc[mi][ni][r]);
            asm volatile("s_waitcnt lgkmcnt(0)" ::: "memory");
            u16* dst = vt + ((size_t)(bb * NHEAD + hq) * HDIM) * T_SEQ + tb;
#pragma unroll
            for (int it = 0; it < 8; it++) {
                int row = it * 8 + l8, col = c8 * 8;
                bf16x8 v = *(const bf16x8*)(ep + row * 72 + col);
                *(bf16x8*)(dst + (size_t)row * T_SEQ + col) = v;
            }
        } else {
            const float sc = which ? 1.f : 0.125f;
#pragma unroll
            for (int mi = 0; mi < MI; mi++)
#pragma unroll
                for (int ni = 0; ni < MI; ni++)
#pragma unroll
                    for (int r = 0; r < 4; r++)
                        ep[(mi * 16 + quad * 4 + r) * 72 + ni * 16 + n16] = f2bf(acc[mi][ni][r] * sc);
            asm volatile("s_waitcnt lgkmcnt(0)" ::: "memory");
            u16* dst = (which ? ko : qo) + ((size_t)(bb * NHEAD + hq) * T_SEQ + tb) * HDIM;
#pragma unroll
            for (int it = 0; it < 8; it++) {
                int row = it * 8 + l8, col = c8 * 8;
                bf16x8 v = *(const bf16x8*)(ep + row * 72 + col);
                *(bf16x8*)(dst + (size_t)row * HDIM + col) = v;
            }
        }
    } else {
        if (*flag == 0) {
            // fp32 output (live path): float4 full-line stores via LDS transpose
            float* epf = (float*)smem + w * (WM * (WM + 4));
#pragma unroll
            for (int mi = 0; mi < MI; mi++)
#pragma unroll
                for (int ni = 0; ni < MI; ni++)
#pragma unroll
                    for (int r = 0; r < 4; r++)
                        epf[(mi * 16 + quad * 4 + r) * (WM + 4) + ni * 16 + n16] = acc[mi][ni][r];
            asm volatile("s_waitcnt lgkmcnt(0)" ::: "memory");
            constexpr int LPR = WM / 4;                 // lanes per row (float4)
            constexpr int RPI = 64 / LPR;               // rows per instruction
#pragma unroll
            for (int it = 0; it < WM / RPI; it++) {
                int row = it * RPI + lane / LPR, col = (lane % LPR) * 4;
                float4 v = *(const float4*)(epf + row * (WM + 4) + col);
                *(float4*)(outf32 + (size_t)(bm + wm + row) * N + bn + wn + col) = v;
            }
        } else {
            u16* ep = smem + w * (WM * 72);
#pragma unroll
            for (int mi = 0; mi < MI; mi++)
#pragma unroll
                for (int ni = 0; ni < MI; ni++)
#pragma unroll
                    for (int r = 0; r < 4; r++)
                        ep[(mi * 16 + quad * 4 + r) * 72 + ni * 16 + n16] = f2bf(acc[mi][ni][r]);
            asm volatile("s_waitcnt lgkmcnt(0)" ::: "memory");
            constexpr int LPR = WM / 8;
            constexpr int RPI = 64 / LPR;
#pragma unroll
            for (int it = 0; it < WM / RPI; it++) {
                int row = it * RPI + lane / LPR, col = (lane % LPR) * 8;
                bf16x8 v = *(const bf16x8*)(ep + row * 72 + col);
                *(bf16x8*)(outb16 + (size_t)(bm + wm + row) * N + bn + wn + col) = v;
            }
        }
    }
}

// MFMA flash attention with cooperative LDS staging of K/V, max-free softmax
// (p = exp(s-10), offset cancels in o/l), denominators via mfma(P, ones).
// 1-D grid of 1024, XCD-aware decode: xcd = lin&7; all 32 q-tile blocks of a
// head land on one XCD (L2 locality for that head's K/V), qt descending
// within each group for tail balance. 4 blocks/CU co-resident.
__global__ __launch_bounds__(256, 4) void attn_mfma(
    const u16* __restrict__ qb, const u16* __restrict__ kb,
    const u16* __restrict__ vt, u16* __restrict__ ob)
{
    __shared__ u16 Ks[64 * 64];        // [t_local][d], XOR-swizzled chunks
    __shared__ u16 Vs[64 * 64];        // [d][t_local], XOR-swizzled chunks
    __shared__ u16 Plds[4][16][72];
    const int NT = T_SEQ / 64;         // 32
    const int lin = blockIdx.x;
    const int xcd = lin & 7;
    const int rest = lin >> 3;
    const int qt = (NT - 1) - (rest & 31);          // descending
    const int bh = ((rest >> 5) << 3) + xcd;        // head group pinned to xcd
    const int w = threadIdx.x >> 6, lane = threadIdx.x & 63;
    const int n16 = lane & 15, quad = lane >> 4;
    const int l8 = lane >> 3, c8 = lane & 7;
    const size_t baseK = (size_t)bh * T_SEQ * HDIM;   // [t][d]
    const size_t baseV = (size_t)bh * HDIM * T_SEQ;   // [d][t]
    const int b = bh >> 4, h = bh & 15;
    const int qrow = qt * 64 + w * 16;

    bf16x8 ones;
#pragma unroll
    for (int j = 0; j < 8; j++) ones[j] = (short)0x3F80;   // bf16 1.0

    // staging: each wave covers 2 row-groups of 8 rows per matrix
    auto stage = [&](int kt) {
#pragma unroll
        for (int i = 0; i < 2; i++) {
            int rowblk = (i * 4 + w) * 8;
            int row = rowblk + l8;
            int gc = (c8 ^ l8) * 8;    // XOR swizzle
            gl_lds16(kb + baseK + (size_t)(kt * 64 + row) * HDIM + gc, Ks + rowblk * 64);
            gl_lds16(vt + baseV + (size_t)row * T_SEQ + kt * 64 + gc, Vs + rowblk * 64);
        }
    };

    bf16x8 qf[2];
#pragma unroll
    for (int ks = 0; ks < 2; ks++)
        qf[ks] = *(const bf16x8*)(qb + baseK + (size_t)(qrow + n16) * HDIM + ks * 32 + quad * 8);

    f32x4 accO[4];
#pragma unroll
    for (int st = 0; st < 4; st++) accO[st] = (f32x4){0.f, 0.f, 0.f, 0.f};
    f32x4 accL = (f32x4){0.f, 0.f, 0.f, 0.f};

    stage(0);
    for (int kt = 0; kt <= qt; kt++) {
        __syncthreads();   // stage(kt) complete (drains vmcnt)

        bf16x8 kf[2][4], vf[2][4];
#pragma unroll
        for (int st = 0; st < 4; st++)
#pragma unroll
            for (int ks = 0; ks < 2; ks++) {
                int off = (st * 16 + n16) * 64 + (((ks * 4 + quad) ^ (n16 & 7)) * 8);
                kf[ks][st] = *(const bf16x8*)(Ks + off);
                vf[ks][st] = *(const bf16x8*)(Vs + off);
            }
        __syncthreads();   // all fragments in registers; K/V LDS free

        if (kt < qt) stage(kt + 1);   // async, lands during compute below

        f32x4 S[4];
#pragma unroll
        for (int st = 0; st < 4; st++) S[st] = (f32x4){0.f, 0.f, 0.f, 0.f};
#pragma unroll
        for (int st = 0; st < 4; st++)
#pragma unroll
            for (int ks = 0; ks < 2; ks++)
                S[st] = __builtin_amdgcn_mfma_f32_16x16x32_bf16(qf[ks], kf[ks][st], S[st], 0, 0, 0);

        if (kt == qt) {   // diagonal tile: causal mask
            int qloc = w * 16 + quad * 4;
#pragma unroll
            for (int st = 0; st < 4; st++) {
                int kloc = st * 16 + n16;
#pragma unroll
                for (int r = 0; r < 4; r++)
                    if (kloc > qloc + r) S[st][r] = -INFINITY;
            }
        }

        // p = exp(s - 10) = exp2(1.4427*s - 14.427); bf16 by truncation
#pragma unroll
        for (int st = 0; st < 4; st++)
#pragma unroll
            for (int r = 0; r < 4; r++) {
                float p = exp2f(__builtin_fmaf(S[st][r], 1.44269504f, -14.4269504f));
                Plds[w][quad * 4 + r][st * 16 + n16] = (u16)(__float_as_uint(p) >> 16);
            }
        asm volatile("s_waitcnt lgkmcnt(0)" ::: "memory");
        bf16x8 pf[2];
#pragma unroll
        for (int ks = 0; ks < 2; ks++)
            pf[ks] = *(const bf16x8*)(&Plds[w][n16][ks * 32 + quad * 8]);

#pragma unroll
        for (int st = 0; st < 4; st++)
#pragma unroll
            for (int ks = 0; ks < 2; ks++)
                accO[st] = __builtin_amdgcn_mfma_f32_16x16x32_bf16(pf[ks], vf[ks][st], accO[st], 0, 0, 0);
#pragma unroll
        for (int ks = 0; ks < 2; ks++)
            accL = __builtin_amdgcn_mfma_f32_16x16x32_bf16(pf[ks], ones, accL, 0, 0, 0);
    }

    // epilogue: normalize, transpose via Plds (wave-private), line stores
#pragma unroll
    for (int r = 0; r < 4; r++) {
        float inv = 1.f / accL[r];
#pragma unroll
        for (int st = 0; st < 4; st++)
            Plds[w][quad * 4 + r][st * 16 + n16] = f2bf(accO[st][r] * inv);
    }
    asm volatile("s_waitcnt lgkmcnt(0)" ::: "memory");
    u16* dst = ob + ((size_t)(b * T_SEQ + qrow)) * 1024 + h * HDIM;
#pragma unroll
    for (int it = 0; it < 2; it++) {
        int row = it * 8 + l8, col = c8 * 8;
        bf16x8 v = *(const bf16x8*)(&Plds[w][row][col]);
        *(bf16x8*)(dst + (size_t)row * 1024 + col) = v;
    }
}

extern "C" void kernel_launch(void* const* d_in, const int* in_sizes, int n_in,
                              void* d_out, int out_size, void* d_ws, size_t ws_size,
                              hipStream_t stream) {
    const void* x    = d_in[0];   // (2,2048,1024)
    const void* Wqkv = d_in[1];   // (3072,1024)
    const void* Wout = d_in[2];   // (1024,1024)

    const int Mtok = NB * T_SEQ;                                  // 4096
    const size_t n_x    = (size_t)Mtok * 1024;
    const size_t n_wqkv = (size_t)3072 * 1024;
    const size_t n_wout = (size_t)1024 * 1024;
    const size_t qkv_elems = (size_t)NB * NHEAD * T_SEQ * HDIM;   // 4,194,304

    u16* xb    = (u16*)d_ws;
    u16* wqkvb = xb + n_x;
    u16* woutb = wqkvb + n_wqkv;
    u16* qb    = woutb + n_wout;
    u16* kb    = qb + qkv_elems;
    u16* vt    = kb + qkv_elems;   // V stored transposed [b,h,d,t]
    u16* obuf  = vt + qkv_elems;
    int* flag  = (int*)(obuf + qkv_elems);

    detect_dtype<<<1, 64, 0, stream>>>((const uint32_t*)x, flag);

    to_bf16<<<1024, 256, 0, stream>>>(x,    xb,    (int)(n_x / 4),    flag);
    to_bf16<<<1024, 256, 0, stream>>>(Wqkv, wqkvb, (int)(n_wqkv / 4), flag);
    to_bf16<<<512,  256, 0, stream>>>(Wout, woutb, (int)(n_wout / 4), flag);

    gemm_bt_mfma<128, 0><<<dim3(3072 / 128, Mtok / 128), 256, 0, stream>>>(
        xb, wqkvb, 3072, 1024, qb, kb, vt, nullptr, nullptr, flag);

    attn_mfma<<<dim3(NB * NHEAD * (T_SEQ / 64)), 256, 0, stream>>>(qb, kb, vt, obuf);

    gemm_bt_mfma<64, 1><<<dim3(1024 / 64, Mtok / 64), 256, 0, stream>>>(
        obuf, woutb, 1024, 1024, nullptr, nullptr, nullptr,
        (u16*)d_out, (float*)d_out, flag);
}

// Round 9
// 169.234 us; speedup vs baseline: 1.3176x; 1.3176x over previous
//
#include <hip/hip_runtime.h>
#include <hip/hip_bf16.h>
#include <cstdint>

typedef unsigned short u16;
typedef __attribute__((ext_vector_type(8))) short bf16x8;
typedef __attribute__((ext_vector_type(4))) float f32x4;

#define T_SEQ 2048
#define NHEAD 16
#define HDIM  64
#define NB    2

__device__ __forceinline__ float bf2f(uint32_t h) { return __uint_as_float(h << 16); }
__device__ __forceinline__ u16 f2bf(float f) {
    uint32_t u = __float_as_uint(f);
    u += 0x7fffu + ((u >> 16) & 1u);
    return (u16)(u >> 16);
}

// async global->LDS, 16B per lane; LDS dest = wave-uniform base + lane*16
__device__ __forceinline__ void gl_lds16(const u16* g, u16* s) {
    __builtin_amdgcn_global_load_lds(
        (const __attribute__((address_space(1))) unsigned int*)g,
        (__attribute__((address_space(3))) unsigned int*)s, 16, 0, 0);
}

// Detect input dtype (parallel): bf16-packed data has low-u16 exponent fields
// clustered near 127; fp32 low halves are ~uniform mantissa bits.
__global__ void detect_dtype(const uint32_t* __restrict__ x, int* __restrict__ flag) {
    __shared__ int red[4];
    int c = 0;
#pragma unroll
    for (int j = 0; j < 4; j++) {
        uint32_t v = x[threadIdx.x * 4 + j];
        uint32_t lo = v & 0xffffu;
        uint32_t e = (lo >> 7) & 0xffu;
        if (lo != 0u && e >= 110u && e <= 135u) c++;
    }
#pragma unroll
    for (int off = 32; off; off >>= 1) c += __shfl_down(c, off);
    if ((threadIdx.x & 63) == 0) red[threadIdx.x >> 6] = c;
    __syncthreads();
    if (threadIdx.x == 0)
        *flag = (red[0] + red[1] + red[2] + red[3] > 614) ? 1 : 0;   // 1=bf16, 0=fp32
}

// vectorized conversion, 4 elements per thread
__global__ __launch_bounds__(256) void to_bf16(
    const void* __restrict__ src, u16* __restrict__ dst, int n4,
    const int* __restrict__ flag)
{
    int i = blockIdx.x * 256 + threadIdx.x;
    const int stride = gridDim.x * 256;
    if (*flag != 0) {
        const uint2* s = (const uint2*)src;
        uint2* d = (uint2*)dst;
        for (; i < n4; i += stride) d[i] = s[i];
    } else {
        const float4* s = (const float4*)src;
        for (; i < n4; i += stride) {
            float4 v = s[i];
            ushort4 o = { f2bf(v.x), f2bf(v.y), f2bf(v.z), f2bf(v.w) };
            *(ushort4*)(dst + (size_t)i * 4) = o;
        }
    }
}

// m97-pattern MFMA GEMM: C = A (MxK bf16 rm) * B^T (B NxK rm), fp32 accum.
// global_load_lds width-16 staging into unpadded [BM][64] LDS tiles with XOR
// swizzle -> conflict-free stride-64 fragment reads. 4 waves in 2x2.
// MODE 0 (BM=128): scatter q [b,h,t,d] (x0.125), k [b,h,t,d], vT [b,h,d,t].
// MODE 1 (BM=64): row-major C; fp32 (flag==0) or bf16 path, full-line stores.
template<int BM, int MODE>
__global__ __launch_bounds__(256, 3) void gemm_bt_mfma(
    const u16* __restrict__ A, const u16* __restrict__ B,
    int N, int K,
    u16* __restrict__ qo, u16* __restrict__ ko, u16* __restrict__ vt,
    u16* __restrict__ outb16, float* __restrict__ outf32,
    const int* __restrict__ flag)
{
    constexpr int WM = BM / 2;
    constexpr int MI = WM / 16;
    constexpr int IA = BM / 32;
    constexpr int ST = 2 * BM * 64 * 2;
    constexpr int E16 = 4 * WM * 72 * 2;
    constexpr int EF = (MODE == 1) ? 4 * WM * (WM + 4) * 4 : 0;
    constexpr int SB = (ST > E16 ? ST : E16) > EF ? (ST > E16 ? ST : E16) : EF;
    __shared__ u16 smem[SB / 2];
    u16* As = smem;            // [BM][64]
    u16* Bs = smem + BM * 64;  // [BM][64]
    const int tid = threadIdx.x;
    const int bm = blockIdx.y * BM, bn = blockIdx.x * BM;
    const int w = tid >> 6, lane = tid & 63;
    const int wm = (w >> 1) * WM, wn = (w & 1) * WM;
    const int n16 = lane & 15, quad = lane >> 4;
    const int l8 = lane >> 3, c8 = lane & 7;

    f32x4 acc[MI][MI];
#pragma unroll
    for (int mi = 0; mi < MI; mi++)
#pragma unroll
        for (int ni = 0; ni < MI; ni++) acc[mi][ni] = (f32x4){0.f, 0.f, 0.f, 0.f};

    const int KT = K >> 6;
    for (int kt = 0; kt < KT; kt++) {
        const int k0 = kt << 6;
#pragma unroll
        for (int i = 0; i < IA; i++) {
            int rowblk = (i * 4 + w) * 8;
            int row = rowblk + l8;
            int gcol = (c8 ^ l8) * 8;   // XOR swizzle
            gl_lds16(A + (size_t)(bm + row) * K + k0 + gcol, As + rowblk * 64);
            gl_lds16(B + (size_t)(bn + row) * K + k0 + gcol, Bs + rowblk * 64);
        }
        __syncthreads();
#pragma unroll
        for (int ks = 0; ks < 2; ks++) {
            bf16x8 af[MI], bfr[MI];
#pragma unroll
            for (int mi = 0; mi < MI; mi++) {
                int row = wm + mi * 16 + n16;
                af[mi] = *(const bf16x8*)(As + row * 64 + (((ks * 4 + quad) ^ (n16 & 7)) * 8));
            }
#pragma unroll
            for (int ni = 0; ni < MI; ni++) {
                int row = wn + ni * 16 + n16;
                bfr[ni] = *(const bf16x8*)(Bs + row * 64 + (((ks * 4 + quad) ^ (n16 & 7)) * 8));
            }
#pragma unroll
            for (int mi = 0; mi < MI; mi++)
#pragma unroll
                for (int ni = 0; ni < MI; ni++)
                    acc[mi][ni] = __builtin_amdgcn_mfma_f32_16x16x32_bf16(
                        af[mi], bfr[ni], acc[mi][ni], 0, 0, 0);
        }
        __syncthreads();
    }

    // Epilogues: per-wave LDS transpose -> full-line stores.
    // C/D layout: col = n16, row = quad*4 + r (HW-verified m89/m91).
    if constexpr (MODE == 0) {
        u16* ep = smem + w * (WM * 72);
        const int which = (bn + wn) >> 10;            // 0=q 1=k 2=v (wave-uniform)
        const int hq = ((bn + wn) & 1023) >> 6;
        const int bb = (bm + wm) >> 11;
        const int tb = (bm + wm) & (T_SEQ - 1);
        if (which == 2) {
#pragma unroll
            for (int mi = 0; mi < MI; mi++)
#pragma unroll
                for (int ni = 0; ni < MI; ni++)
#pragma unroll
                    for (int r = 0; r < 4; r++)
                        ep[(ni * 16 + n16) * 72 + mi * 16 + quad * 4 + r] = f2bf(acc[mi][ni][r]);
            asm volatile("s_waitcnt lgkmcnt(0)" ::: "memory");
            u16* dst = vt + ((size_t)(bb * NHEAD + hq) * HDIM) * T_SEQ + tb;
#pragma unroll
            for (int it = 0; it < 8; it++) {
                int row = it * 8 + l8, col = c8 * 8;
                bf16x8 v = *(const bf16x8*)(ep + row * 72 + col);
                *(bf16x8*)(dst + (size_t)row * T_SEQ + col) = v;
            }
        } else {
            const float sc = which ? 1.f : 0.125f;
#pragma unroll
            for (int mi = 0; mi < MI; mi++)
#pragma unroll
                for (int ni = 0; ni < MI; ni++)
#pragma unroll
                    for (int r = 0; r < 4; r++)
                        ep[(mi * 16 + quad * 4 + r) * 72 + ni * 16 + n16] = f2bf(acc[mi][ni][r] * sc);
            asm volatile("s_waitcnt lgkmcnt(0)" ::: "memory");
            u16* dst = (which ? ko : qo) + ((size_t)(bb * NHEAD + hq) * T_SEQ + tb) * HDIM;
#pragma unroll
            for (int it = 0; it < 8; it++) {
                int row = it * 8 + l8, col = c8 * 8;
                bf16x8 v = *(const bf16x8*)(ep + row * 72 + col);
                *(bf16x8*)(dst + (size_t)row * HDIM + col) = v;
            }
        }
    } else {
        if (*flag == 0) {
            float* epf = (float*)smem + w * (WM * (WM + 4));
#pragma unroll
            for (int mi = 0; mi < MI; mi++)
#pragma unroll
                for (int ni = 0; ni < MI; ni++)
#pragma unroll
                    for (int r = 0; r < 4; r++)
                        epf[(mi * 16 + quad * 4 + r) * (WM + 4) + ni * 16 + n16] = acc[mi][ni][r];
            asm volatile("s_waitcnt lgkmcnt(0)" ::: "memory");
            constexpr int LPR = WM / 4;
            constexpr int RPI = 64 / LPR;
#pragma unroll
            for (int it = 0; it < WM / RPI; it++) {
                int row = it * RPI + lane / LPR, col = (lane % LPR) * 4;
                float4 v = *(const float4*)(epf + row * (WM + 4) + col);
                *(float4*)(outf32 + (size_t)(bm + wm + row) * N + bn + wn + col) = v;
            }
        } else {
            u16* ep = smem + w * (WM * 72);
#pragma unroll
            for (int mi = 0; mi < MI; mi++)
#pragma unroll
                for (int ni = 0; ni < MI; ni++)
#pragma unroll
                    for (int r = 0; r < 4; r++)
                        ep[(mi * 16 + quad * 4 + r) * 72 + ni * 16 + n16] = f2bf(acc[mi][ni][r]);
            asm volatile("s_waitcnt lgkmcnt(0)" ::: "memory");
            constexpr int LPR = WM / 8;
            constexpr int RPI = 64 / LPR;
#pragma unroll
            for (int it = 0; it < WM / RPI; it++) {
                int row = it * RPI + lane / LPR, col = (lane % LPR) * 8;
                bf16x8 v = *(const bf16x8*)(ep + row * 72 + col);
                *(bf16x8*)(outb16 + (size_t)(bm + wm + row) * N + bn + wn + col) = v;
            }
        }
    }
}

// MFMA flash attention: paired q-tiles (p, 31-p) SHARING one staged K/V tile
// stream (one kt loop to qtb; small tile gated by kt<=qts) -> uniform 33
// compute-units/block, ~24.5 staged tiles avg, 2x MFMA per staged tile.
// XCD-pinned decode: bh = grp*8 + (lin&7) keeps each head's K/V in one XCD L2.
// Max-free softmax (p=exp(s-10), cancels in o/l); denominators via mfma(P,1).
__global__ __launch_bounds__(256, 2) void attn_mfma(
    const u16* __restrict__ qb, const u16* __restrict__ kb,
    const u16* __restrict__ vt, u16* __restrict__ ob)
{
    __shared__ u16 Ks[64 * 64];        // [t_local][d], XOR-swizzled chunks
    __shared__ u16 Vs[64 * 64];        // [d][t_local], XOR-swizzled chunks
    __shared__ u16 Plds[4][16][72];
    const int lin = blockIdx.x;        // 0..511
    const int xcd = lin & 7;
    const int rest = lin >> 3;         // 0..63
    const int p = rest & 15;
    const int grp = rest >> 4;         // 0..3
    const int bh = grp * 8 + xcd;      // head pinned to xcd group
    const int qtb = 31 - p, qts = p;   // big / small q-tile
    const int w = threadIdx.x >> 6, lane = threadIdx.x & 63;
    const int n16 = lane & 15, quad = lane >> 4;
    const int l8 = lane >> 3, c8 = lane & 7;
    const size_t baseK = (size_t)bh * T_SEQ * HDIM;   // [t][d]
    const size_t baseV = (size_t)bh * HDIM * T_SEQ;   // [d][t]
    const int b = bh >> 4, h = bh & 15;

    bf16x8 ones;
#pragma unroll
    for (int j = 0; j < 8; j++) ones[j] = (short)0x3F80;   // bf16 1.0

    auto stage = [&](int kt) {
#pragma unroll
        for (int i = 0; i < 2; i++) {
            int rowblk = (i * 4 + w) * 8;
            int row = rowblk + l8;
            int gc = (c8 ^ l8) * 8;    // XOR swizzle
            gl_lds16(kb + baseK + (size_t)(kt * 64 + row) * HDIM + gc, Ks + rowblk * 64);
            gl_lds16(vt + baseV + (size_t)row * T_SEQ + kt * 64 + gc, Vs + rowblk * 64);
        }
    };

    const int qrowb = qtb * 64 + w * 16, qrows = qts * 64 + w * 16;
    bf16x8 qfb[2], qfs[2];
#pragma unroll
    for (int ks = 0; ks < 2; ks++) {
        qfb[ks] = *(const bf16x8*)(qb + baseK + (size_t)(qrowb + n16) * HDIM + ks * 32 + quad * 8);
        qfs[ks] = *(const bf16x8*)(qb + baseK + (size_t)(qrows + n16) * HDIM + ks * 32 + quad * 8);
    }

    f32x4 accOb[4], accOs[4];
#pragma unroll
    for (int st = 0; st < 4; st++) {
        accOb[st] = (f32x4){0.f, 0.f, 0.f, 0.f};
        accOs[st] = (f32x4){0.f, 0.f, 0.f, 0.f};
    }
    f32x4 accLb = (f32x4){0.f, 0.f, 0.f, 0.f};
    f32x4 accLs = (f32x4){0.f, 0.f, 0.f, 0.f};

    stage(0);
    for (int kt = 0; kt <= qtb; kt++) {
        __syncthreads();   // stage(kt) complete (drains vmcnt)

        bf16x8 kf[2][4], vf[2][4];
#pragma unroll
        for (int st = 0; st < 4; st++)
#pragma unroll
            for (int ks = 0; ks < 2; ks++) {
                int off = (st * 16 + n16) * 64 + (((ks * 4 + quad) ^ (n16 & 7)) * 8);
                kf[ks][st] = *(const bf16x8*)(Ks + off);
                vf[ks][st] = *(const bf16x8*)(Vs + off);
            }
        __syncthreads();   // fragments in registers; K/V LDS free

        if (kt < qtb) stage(kt + 1);   // async, lands during compute below

        // ---- big q-tile ----
        {
            f32x4 S[4];
#pragma unroll
            for (int st = 0; st < 4; st++) S[st] = (f32x4){0.f, 0.f, 0.f, 0.f};
#pragma unroll
            for (int st = 0; st < 4; st++)
#pragma unroll
                for (int ks = 0; ks < 2; ks++)
                    S[st] = __builtin_amdgcn_mfma_f32_16x16x32_bf16(qfb[ks], kf[ks][st], S[st], 0, 0, 0);
            if (kt == qtb) {
                int qloc = w * 16 + quad * 4;
#pragma unroll
                for (int st = 0; st < 4; st++) {
                    int kloc = st * 16 + n16;
#pragma unroll
                    for (int r = 0; r < 4; r++)
                        if (kloc > qloc + r) S[st][r] = -INFINITY;
                }
            }
#pragma unroll
            for (int st = 0; st < 4; st++)
#pragma unroll
                for (int r = 0; r < 4; r++) {
                    float pv = exp2f(__builtin_fmaf(S[st][r], 1.44269504f, -14.4269504f));
                    Plds[w][quad * 4 + r][st * 16 + n16] = (u16)(__float_as_uint(pv) >> 16);
                }
            asm volatile("s_waitcnt lgkmcnt(0)" ::: "memory");
            bf16x8 pf[2];
#pragma unroll
            for (int ks = 0; ks < 2; ks++)
                pf[ks] = *(const bf16x8*)(&Plds[w][n16][ks * 32 + quad * 8]);
#pragma unroll
            for (int st = 0; st < 4; st++)
#pragma unroll
                for (int ks = 0; ks < 2; ks++)
                    accOb[st] = __builtin_amdgcn_mfma_f32_16x16x32_bf16(pf[ks], vf[ks][st], accOb[st], 0, 0, 0);
#pragma unroll
            for (int ks = 0; ks < 2; ks++)
                accLb = __builtin_amdgcn_mfma_f32_16x16x32_bf16(pf[ks], ones, accLb, 0, 0, 0);
        }

        // ---- small q-tile (shares this staged K/V) ----
        if (kt <= qts) {
            f32x4 S[4];
#pragma unroll
            for (int st = 0; st < 4; st++) S[st] = (f32x4){0.f, 0.f, 0.f, 0.f};
#pragma unroll
            for (int st = 0; st < 4; st++)
#pragma unroll
                for (int ks = 0; ks < 2; ks++)
                    S[st] = __builtin_amdgcn_mfma_f32_16x16x32_bf16(qfs[ks], kf[ks][st], S[st], 0, 0, 0);
            if (kt == qts) {
                int qloc = w * 16 + quad * 4;
#pragma unroll
                for (int st = 0; st < 4; st++) {
                    int kloc = st * 16 + n16;
#pragma unroll
                    for (int r = 0; r < 4; r++)
                        if (kloc > qloc + r) S[st][r] = -INFINITY;
                }
            }
#pragma unroll
            for (int st = 0; st < 4; st++)
#pragma unroll
                for (int r = 0; r < 4; r++) {
                    float pv = exp2f(__builtin_fmaf(S[st][r], 1.44269504f, -14.4269504f));
                    Plds[w][quad * 4 + r][st * 16 + n16] = (u16)(__float_as_uint(pv) >> 16);
                }
            asm volatile("s_waitcnt lgkmcnt(0)" ::: "memory");
            bf16x8 pf[2];
#pragma unroll
            for (int ks = 0; ks < 2; ks++)
                pf[ks] = *(const bf16x8*)(&Plds[w][n16][ks * 32 + quad * 8]);
#pragma unroll
            for (int st = 0; st < 4; st++)
#pragma unroll
                for (int ks = 0; ks < 2; ks++)
                    accOs[st] = __builtin_amdgcn_mfma_f32_16x16x32_bf16(pf[ks], vf[ks][st], accOs[st], 0, 0, 0);
#pragma unroll
            for (int ks = 0; ks < 2; ks++)
                accLs = __builtin_amdgcn_mfma_f32_16x16x32_bf16(pf[ks], ones, accLs, 0, 0, 0);
        }
    }

    // epilogues: normalize, transpose via Plds (wave-private), line stores
#pragma unroll
    for (int r = 0; r < 4; r++) {
        float inv = 1.f / accLb[r];
#pragma unroll
        for (int st = 0; st < 4; st++)
            Plds[w][quad * 4 + r][st * 16 + n16] = f2bf(accOb[st][r] * inv);
    }
    asm volatile("s_waitcnt lgkmcnt(0)" ::: "memory");
    u16* dstb = ob + ((size_t)(b * T_SEQ + qrowb)) * 1024 + h * HDIM;
#pragma unroll
    for (int it = 0; it < 2; it++) {
        int row = it * 8 + l8, col = c8 * 8;
        bf16x8 v = *(const bf16x8*)(&Plds[w][row][col]);
        *(bf16x8*)(dstb + (size_t)row * 1024 + col) = v;
    }
    asm volatile("s_waitcnt lgkmcnt(0)" ::: "memory");   // stores read Plds before overwrite? (vm) — LDS reads already done
#pragma unroll
    for (int r = 0; r < 4; r++) {
        float inv = 1.f / accLs[r];
#pragma unroll
        for (int st = 0; st < 4; st++)
            Plds[w][quad * 4 + r][st * 16 + n16] = f2bf(accOs[st][r] * inv);
    }
    asm volatile("s_waitcnt lgkmcnt(0)" ::: "memory");
    u16* dsts = ob + ((size_t)(b * T_SEQ + qrows)) * 1024 + h * HDIM;
#pragma unroll
    for (int it = 0; it < 2; it++) {
        int row = it * 8 + l8, col = c8 * 8;
        bf16x8 v = *(const bf16x8*)(&Plds[w][row][col]);
        *(bf16x8*)(dsts + (size_t)row * 1024 + col) = v;
    }
}

extern "C" void kernel_launch(void* const* d_in, const int* in_sizes, int n_in,
                              void* d_out, int out_size, void* d_ws, size_t ws_size,
                              hipStream_t stream) {
    const void* x    = d_in[0];   // (2,2048,1024)
    const void* Wqkv = d_in[1];   // (3072,1024)
    const void* Wout = d_in[2];   // (1024,1024)

    const int Mtok = NB * T_SEQ;                                  // 4096
    const size_t n_x    = (size_t)Mtok * 1024;
    const size_t n_wqkv = (size_t)3072 * 1024;
    const size_t n_wout = (size_t)1024 * 1024;
    const size_t qkv_elems = (size_t)NB * NHEAD * T_SEQ * HDIM;   // 4,194,304

    u16* xb    = (u16*)d_ws;
    u16* wqkvb = xb + n_x;
    u16* woutb = wqkvb + n_wqkv;
    u16* qb    = woutb + n_wout;
    u16* kb    = qb + qkv_elems;
    u16* vt    = kb + qkv_elems;   // V stored transposed [b,h,d,t]
    u16* obuf  = vt + qkv_elems;
    int* flag  = (int*)(obuf + qkv_elems);

    detect_dtype<<<1, 256, 0, stream>>>((const uint32_t*)x, flag);

    to_bf16<<<1024, 256, 0, stream>>>(x,    xb,    (int)(n_x / 4),    flag);
    to_bf16<<<1024, 256, 0, stream>>>(Wqkv, wqkvb, (int)(n_wqkv / 4), flag);
    to_bf16<<<512,  256, 0, stream>>>(Wout, woutb, (int)(n_wout / 4), flag);

    gemm_bt_mfma<128, 0><<<dim3(3072 / 128, Mtok / 128), 256, 0, stream>>>(
        xb, wqkvb, 3072, 1024, qb, kb, vt, nullptr, nullptr, flag);

    attn_mfma<<<dim3(NB * NHEAD * (T_SEQ / 128)), 256, 0, stream>>>(qb, kb, vt, obuf);

    gemm_bt_mfma<64, 1><<<dim3(1024 / 64, Mtok / 64), 256, 0, stream>>>(
        obuf, woutb, 1024, 1024, nullptr, nullptr, nullptr,
        (u16*)d_out, (float*)d_out, flag);
}